// Round 3
// baseline (593.468 us; speedup 1.0000x reference)
//
#include <hip/hip_runtime.h>
#include <hip/hip_bf16.h>
#include <cstdint>
#include <cstddef>

// ---------------------------------------------------------------------------
// EinsteinCore: hyperbolic attention, MI355X fp16-MFMA implementation. v2r
// (identical to v2 — previous bench was an infra failure, not a kernel one).
// B=8, S=M=2048, K_in=1024, DH=DOUT=512, k=1, beta=1/sqrt(512).
//
// v2 changes vs v1 (theory: attn was barrier-latency-bound, proj LLC-bound):
//  - k_attn: no LDS staging for K/V. Fragments read directly from global
//    (each frag = 16B/lane, 4 q-lanes cover a full 64B line). m-tile 64,
//    m-partitioned across 4 waves (K/V read ONCE per block). Q (32 rows)
//    resident in registers. P double-buffered -> ONE barrier per iteration.
//    XCD swizzle: batch = blk&7 pins each batch's 4MB K+V set to one XCD L2.
//  - k_proj: 128 rows x all 512 cols per block (X fp32 read exactly once),
//    BK=64, W pre-cast to f16 and staged via global_load_lds(16B) with XOR
//    swizzle; rowstats (cosh/f per row) fused into the epilogue.
// ---------------------------------------------------------------------------

typedef _Float16 f16x8 __attribute__((ext_vector_type(8)));
typedef _Float16 f16x4 __attribute__((ext_vector_type(4)));
typedef float    f32x4 __attribute__((ext_vector_type(4)));

#define BETA_F 0.04419417382415922f
#define LOG2E_F 1.4426950408889634f
#define LN2_F 0.6931471805599453f

__device__ __forceinline__ void gload_lds16(const void* g, void* l) {
  __builtin_amdgcn_global_load_lds(
      (__attribute__((address_space(1))) void*)(g),
      (__attribute__((address_space(3))) void*)(l), 16, 0, 0);
}

// ---------------------------------------------------------------------------
// K0: cast W (3 x 512x1024 fp32) -> f16.
// ---------------------------------------------------------------------------
__global__ __launch_bounds__(256) void k_wcast(
    const float* __restrict__ wq, const float* __restrict__ wk,
    const float* __restrict__ wv, _Float16* __restrict__ Wh)
{
  const int a = blockIdx.y;
  const float* src = (a == 0) ? wq : ((a == 1) ? wk : wv);
  const int idx = (blockIdx.x * 256 + threadIdx.x) * 8;
  float4 v0 = *(const float4*)(src + idx);
  float4 v1 = *(const float4*)(src + idx + 4);
  f16x8 h = { (_Float16)v0.x, (_Float16)v0.y, (_Float16)v0.z, (_Float16)v0.w,
              (_Float16)v1.x, (_Float16)v1.y, (_Float16)v1.z, (_Float16)v1.w };
  *(f16x8*)(Wh + (size_t)a * 524288 + idx) = h;
}

// ---------------------------------------------------------------------------
// K1: projection GEMM. Block = 128 rows x ALL 512 cols (X read once), BK=64,
// 512 threads (8 waves: wm = w&1 row-half, wn = w>>1 col-quarter).
// Epilogue: bias add, f16 store, fused per-row expmap scalars -> fc2[r].
// ---------------------------------------------------------------------------
#define APIT 72   // f16 pitch for A tile (BK=64 + 8 pad)

__global__ __launch_bounds__(512, 2) void k_proj(
    const float* __restrict__ xq, const float* __restrict__ xk, const float* __restrict__ xv,
    const _Float16* __restrict__ Wh,
    const float* __restrict__ bq, const float* __restrict__ bk, const float* __restrict__ bv,
    _Float16* __restrict__ proj, float2* __restrict__ fc2)
{
  __shared__ __align__(16) _Float16 As[128 * APIT];   // 18 KB
  __shared__ __align__(16) _Float16 Bs[512 * 64];     // 64 KB, xor-swizzled chunks
  __shared__ float ssq[128];

  const int tid = threadIdx.x;
  const int w = tid >> 6, l = tid & 63, ln = l & 15, q = l >> 4;
  const int wm = w & 1, wn = w >> 1;
  const int r0 = blockIdx.x * 128;
  const int which = r0 >> 14;
  const int rloc = r0 & 16383;
  const float* X = (which == 0) ? xq : ((which == 1) ? xk : xv);
  const _Float16* Whb = Wh + (size_t)which * 524288;
  const float* bias = (which == 0) ? bq : ((which == 1) ? bk : bv);

  if (tid < 128) ssq[tid] = 0.f;

  f32x4 acc[4][8];
#pragma unroll
  for (int mt = 0; mt < 4; ++mt)
#pragma unroll
    for (int nt = 0; nt < 8; ++nt) acc[mt][nt] = f32x4{0.f, 0.f, 0.f, 0.f};

  const int arow = tid >> 2, akq = tid & 3;
  for (int kk = 0; kk < 1024; kk += 64) {
    __syncthreads();
    // A stage: fp32 -> f16 (128 x 64), 4 float4 + 2 b128 stores per thread
    {
      const float* xp = X + (size_t)(rloc + arow) * 1024 + kk + akq * 16;
      float4 a0 = *(const float4*)(xp);
      float4 a1 = *(const float4*)(xp + 4);
      float4 a2 = *(const float4*)(xp + 8);
      float4 a3 = *(const float4*)(xp + 12);
      f16x8 h0 = { (_Float16)a0.x, (_Float16)a0.y, (_Float16)a0.z, (_Float16)a0.w,
                   (_Float16)a1.x, (_Float16)a1.y, (_Float16)a1.z, (_Float16)a1.w };
      f16x8 h1 = { (_Float16)a2.x, (_Float16)a2.y, (_Float16)a2.z, (_Float16)a2.w,
                   (_Float16)a3.x, (_Float16)a3.y, (_Float16)a3.z, (_Float16)a3.w };
      *(f16x8*)&As[arow * APIT + akq * 16] = h0;
      *(f16x8*)&As[arow * APIT + akq * 16 + 8] = h1;
    }
    // B stage: Wh (512 x 64) via global_load_lds, chunk xor-swizzle vs row
#pragma unroll
    for (int j = 0; j < 8; ++j) {
      int u = w * 8 + j;
      int row = u * 8 + (l >> 3);
      int cg = (l & 7) ^ (row & 7);
      gload_lds16(Whb + (size_t)row * 1024 + kk + cg * 8, &Bs[u * 512]);
    }
    __syncthreads();
#pragma unroll
    for (int kc = 0; kc < 2; ++kc) {
      f16x8 af[4], bf[8];
#pragma unroll
      for (int mt = 0; mt < 4; ++mt)
        af[mt] = *(const f16x8*)&As[(wm * 64 + mt * 16 + ln) * APIT + kc * 32 + q * 8];
#pragma unroll
      for (int nt = 0; nt < 8; ++nt) {
        int row = wn * 128 + nt * 16 + ln;
        bf[nt] = *(const f16x8*)&Bs[row * 64 + (((kc * 4 + q) ^ (row & 7)) * 8)];
      }
#pragma unroll
      for (int mt = 0; mt < 4; ++mt)
#pragma unroll
        for (int nt = 0; nt < 8; ++nt)
          acc[mt][nt] = __builtin_amdgcn_mfma_f32_16x16x32_f16(af[mt], bf[nt], acc[mt][nt], 0, 0, 0);
    }
  }

  float bl[8];
#pragma unroll
  for (int nt = 0; nt < 8; ++nt) bl[nt] = bias[wn * 128 + nt * 16 + ln];
#pragma unroll
  for (int mt = 0; mt < 4; ++mt)
#pragma unroll
    for (int i = 0; i < 4; ++i) {
      float ss = 0.f;
#pragma unroll
      for (int nt = 0; nt < 8; ++nt) {
        float v = acc[mt][nt][i] + bl[nt];
        proj[(size_t)(r0 + wm * 64 + mt * 16 + q * 4 + i) * 512 + wn * 128 + nt * 16 + ln] =
            (_Float16)v;
        ss += v * v;
      }
      ss += __shfl_xor(ss, 1, 64); ss += __shfl_xor(ss, 2, 64);
      ss += __shfl_xor(ss, 4, 64); ss += __shfl_xor(ss, 8, 64);
      if (ln == 0) atomicAdd(&ssq[wm * 64 + mt * 16 + q * 4 + i], ss);
    }
  __syncthreads();
  if (tid < 128) {
    float n = sqrtf(ssq[tid]);
    float s = fminf(3.5f / (n + 1e-7f), 1.0f);
    float vn = fmaxf(n * s, 1e-12f);
    float e = __builtin_amdgcn_exp2f(vn * LOG2E_F);
    float ie = 1.0f / e;
    fc2[r0 + tid] = make_float2(0.5f * (e + ie), 0.5f * (e - ie) * s / vn);
  }
}

// ---------------------------------------------------------------------------
// K2: transpose V-projection to xvT[b][d][m] (m-contiguous for PV B-frags).
// ---------------------------------------------------------------------------
#define K2_TP 72

__global__ __launch_bounds__(256) void k_transpose_v(
    const _Float16* __restrict__ proj, _Float16* __restrict__ xvT)
{
  __shared__ __align__(16) unsigned short t[64 * K2_TP];
  const int b = blockIdx.z, m0 = blockIdx.x * 64, d0 = blockIdx.y * 64;
  const unsigned short* pv =
      (const unsigned short*)(proj + (size_t)(32768 + b * 2048 + m0) * 512);
#pragma unroll
  for (int it = 0; it < 2; ++it) {
    int v = threadIdx.x + 256 * it;
    int r = v >> 3, c4 = v & 7;
    uint4 dd = *(const uint4*)(pv + (size_t)r * 512 + d0 + c4 * 8);
    *(uint4*)&t[r * K2_TP + c4 * 8] = dd;
  }
  __syncthreads();
#pragma unroll
  for (int it = 0; it < 2; ++it) {
    int v = threadIdx.x + 256 * it;
    int dr = v >> 3, mc = v & 7;
    unsigned int o[4];
#pragma unroll
    for (int jj = 0; jj < 4; ++jj) {
      unsigned int lo = t[(mc * 8 + jj * 2) * K2_TP + dr];
      unsigned int hi = t[(mc * 8 + jj * 2 + 1) * K2_TP + dr];
      o[jj] = lo | (hi << 16);
    }
    uint4 dd = { o[0], o[1], o[2], o[3] };
    unsigned short* dst =
        (unsigned short*)(xvT + ((size_t)b * 512 + d0 + dr) * 2048 + m0 + mc * 8);
    *(uint4*)dst = dd;
  }
}

// ---------------------------------------------------------------------------
// K3: fused hyperbolic attention, global-direct fragments.
// Block = 32 s-rows, 256 threads (4 waves). m-tile 64, wave w owns
// m-chunk [w*16,w*16+16) for QK and d-chunk [w*128,(w+1)*128) for PV.
// Q 32 rows resident in regs. P double-buffered -> 1 barrier/iter.
// ---------------------------------------------------------------------------
#define PPIT 72

__global__ __launch_bounds__(256, 2) void k_attn(
    const _Float16* __restrict__ proj, const _Float16* __restrict__ xvT,
    const float2* __restrict__ fc2, float* __restrict__ out)
{
  __shared__ __align__(16) _Float16 P[2][32 * PPIT];   // 9.2 KB total
  __shared__ float s_den[4][32];
  __shared__ float s_mn2[4][32];
  __shared__ float s_g[32];

  const int tid = threadIdx.x;
  const int w = tid >> 6, l = tid & 63, ln = l & 15, q = l >> 4;
  const int blk = blockIdx.x;
  const int b = blk & 7;                 // XCD swizzle: batch pinned to XCD
  const int s0 = (blk >> 3) * 32;

  const _Float16* projq = proj + (size_t)(b * 2048 + s0) * 512;
  const _Float16* projk = proj + (size_t)(16384 + b * 2048) * 512;
  const _Float16* vt = xvT + (size_t)b * 512 * 2048;
  const float2* fcq = fc2 + b * 2048 + s0;
  const float2* fck = fc2 + 16384 + b * 2048;
  const float2* fcv = fc2 + 32768 + b * 2048;

  // Q fragments in registers: A-frag rows = st*16+ln, k = kc*32+q*8.
  f16x8 qf[2][16];
#pragma unroll
  for (int st = 0; st < 2; ++st) {
    const _Float16* qrow = projq + (size_t)(st * 16 + ln) * 512 + q * 8;
#pragma unroll
    for (int kc = 0; kc < 16; ++kc) qf[st][kc] = *(const f16x8*)(qrow + kc * 32);
  }
  float cq_i[2][4], fq_i[2][4];
#pragma unroll
  for (int st = 0; st < 2; ++st)
#pragma unroll
    for (int i = 0; i < 4; ++i) {
      float2 t = fcq[st * 16 + q * 4 + i];
      cq_i[st][i] = t.x; fq_i[st][i] = t.y;
    }

  f32x4 acc[2][8];
#pragma unroll
  for (int st = 0; st < 2; ++st)
#pragma unroll
    for (int dt = 0; dt < 8; ++dt) acc[st][dt] = f32x4{0.f, 0.f, 0.f, 0.f};
  float den_acc[2][4] = {{0.f,0.f,0.f,0.f},{0.f,0.f,0.f,0.f}};

  for (int it = 0; it < 32; ++it) {
    const int m0 = it * 64;
    _Float16* Pc = P[it & 1];
    const int mla = m0 + w * 16 + ln;

    // --- QK: wave's 16-m chunk, K frags straight from global (L2) ---
    f32x4 pacc0 = f32x4{0.f,0.f,0.f,0.f}, pacc1 = f32x4{0.f,0.f,0.f,0.f};
    {
      const _Float16* krow = projk + (size_t)mla * 512 + q * 8;
#pragma unroll
      for (int kc = 0; kc < 16; ++kc) {
        f16x8 kf = *(const f16x8*)(krow + kc * 32);
        pacc0 = __builtin_amdgcn_mfma_f32_16x16x32_f16(qf[0][kc], kf, pacc0, 0, 0, 0);
        pacc1 = __builtin_amdgcn_mfma_f32_16x16x32_f16(qf[1][kc], kf, pacc1, 0, 0, 0);
      }
    }
    // --- score epilogue ---
    float2 ks = fck[mla];
    float2 vs = fcv[mla];
#pragma unroll
    for (int st = 0; st < 2; ++st) {
      const f32x4& pa = st ? pacc1 : pacc0;
#pragma unroll
      for (int i = 0; i < 4; ++i) {
        float x = cq_i[st][i] * ks.x - (fq_i[st][i] * ks.y) * pa[i];
        x = fmaxf(x, 1.0f + 1e-7f);
        float r_ = x + __builtin_amdgcn_sqrtf(x * x - 1.0f);
        float p = __builtin_amdgcn_exp2f(-BETA_F * __builtin_amdgcn_logf(r_));
        den_acc[st][i] += p * vs.x;
        Pc[(st * 16 + q * 4 + i) * PPIT + w * 16 + ln] = (_Float16)(p * vs.y);
      }
    }
    __syncthreads();                    // P[cur] visible (sole barrier)
    // --- PV: V frags straight from global, wave's 128-d chunk ---
#pragma unroll
    for (int kc2 = 0; kc2 < 2; ++kc2) {
      f16x8 pf0 = *(const f16x8*)&Pc[(ln) * PPIT + kc2 * 32 + q * 8];
      f16x8 pf1 = *(const f16x8*)&Pc[(16 + ln) * PPIT + kc2 * 32 + q * 8];
      const _Float16* vb = vt + (size_t)(w * 128 + ln) * 2048 + m0 + kc2 * 32 + q * 8;
#pragma unroll
      for (int dt = 0; dt < 8; ++dt) {
        f16x8 vf = *(const f16x8*)(vb + (size_t)dt * 16 * 2048);
        acc[0][dt] = __builtin_amdgcn_mfma_f32_16x16x32_f16(pf0, vf, acc[0][dt], 0, 0, 0);
        acc[1][dt] = __builtin_amdgcn_mfma_f32_16x16x32_f16(pf1, vf, acc[1][dt], 0, 0, 0);
      }
    }
  }

  // ---- den: reduce over 16 m-lanes, then over 4 wave m-chunks ----
#pragma unroll
  for (int st = 0; st < 2; ++st)
#pragma unroll
    for (int i = 0; i < 4; ++i) {
      float v = den_acc[st][i];
      v += __shfl_xor(v, 1, 64); v += __shfl_xor(v, 2, 64);
      v += __shfl_xor(v, 4, 64); v += __shfl_xor(v, 8, 64);
      if (ln == 0) s_den[w][st * 16 + q * 4 + i] = v;
    }
  __syncthreads();
  if (tid < 32) {
    float dv = fmaxf(s_den[0][tid] + s_den[1][tid] + s_den[2][tid] + s_den[3][tid], 1e-12f);
    s_den[0][tid] = 1.0f / dv;
  }
  __syncthreads();
  // ---- ||mid||^2 partials (wave owns d-chunk w*128) ----
#pragma unroll
  for (int st = 0; st < 2; ++st)
#pragma unroll
    for (int i = 0; i < 4; ++i) {
      int s = st * 16 + q * 4 + i;
      float inv = s_den[0][s];
      float mm = 0.f;
#pragma unroll
      for (int dt = 0; dt < 8; ++dt) {
        float mid = acc[st][dt][i] * inv;
        mm += mid * mid;
      }
      mm += __shfl_xor(mm, 1, 64); mm += __shfl_xor(mm, 2, 64);
      mm += __shfl_xor(mm, 4, 64); mm += __shfl_xor(mm, 8, 64);
      if (ln == 0) s_mn2[w][s] = mm;
    }
  __syncthreads();
  if (tid < 32) {
    float mn2 = s_mn2[0][tid] + s_mn2[1][tid] + s_mn2[2][tid] + s_mn2[3][tid];
    float mn = sqrtf(mn2);
    float sc = (mn >= 1.0f) ? (1.0f - 1e-6f) / mn : 1.0f;
    float mn2c = fminf(mn2 * sc * sc, 1.0f - 1e-6f);
    float z0 = 1.0f / sqrtf(fmaxf(1.0f - mn2c, 1e-12f));
    float zc = fmaxf(z0, 1.0f + 1e-7f);
    float d0 = LN2_F * __builtin_amdgcn_logf(zc + __builtin_amdgcn_sqrtf(zc * zc - 1.0f));
    s_g[tid] = (d0 / fmaxf(mn, 1e-12f)) * s_den[0][tid];
  }
  __syncthreads();

  // ---- transpose 2 s-rows at a time through LDS, coalesced float4 stores ----
  float* pbuf = (float*)P;               // 9.2 KB dead buffer, need 4 KB
  for (int sp = 0; sp < 16; ++sp) {
#pragma unroll
    for (int st = 0; st < 2; ++st)
#pragma unroll
      for (int i = 0; i < 4; ++i) {
        int s = st * 16 + q * 4 + i;
        if ((s >> 1) == sp) {
          float gg = s_g[s];
#pragma unroll
          for (int dt = 0; dt < 8; ++dt)
            pbuf[(s & 1) * 512 + w * 128 + dt * 16 + ln] = gg * acc[st][dt][i];
        }
      }
    __syncthreads();
    {
      int row = tid >> 7, c4 = tid & 127;
      float4 vv = *(float4*)&pbuf[row * 512 + c4 * 4];
      *(float4*)&out[((size_t)(b * 2048 + s0 + sp * 2 + row)) * 512 + c4 * 4] = vv;
    }
    __syncthreads();
  }
}

// ---------------------------------------------------------------------------
// Workspace layout (bytes) — identical footprint to v1 (67,502,080):
//   [0, 50331648)            proj f16  [49152][512]
//   [50331648, 67108864)     Wh f16 [3][512][1024] (3.1MB), then xvT f16
//                            [8][512][2048] overlays it (Wh dead by then)
//   [67108864, 67502080)     fc2 float2 [49152]  (c0, f)
// ---------------------------------------------------------------------------
extern "C" void kernel_launch(void* const* d_in, const int* in_sizes, int n_in,
                              void* d_out, int out_size, void* d_ws, size_t ws_size,
                              hipStream_t stream) {
  (void)in_sizes; (void)n_in; (void)out_size; (void)ws_size;
  const float* xq = (const float*)d_in[0];
  const float* xk = (const float*)d_in[1];
  const float* xv = (const float*)d_in[2];
  const float* wq = (const float*)d_in[3];
  const float* bq = (const float*)d_in[4];
  const float* wk = (const float*)d_in[5];
  const float* bk = (const float*)d_in[6];
  const float* wv = (const float*)d_in[7];
  const float* bv = (const float*)d_in[8];
  float* out = (float*)d_out;
  char* ws = (char*)d_ws;

  _Float16* proj = (_Float16*)(ws);
  _Float16* Wh   = (_Float16*)(ws + 50331648);
  _Float16* xvT  = (_Float16*)(ws + 50331648);
  float2* fc2    = (float2*)(ws + 67108864);

  k_wcast<<<dim3(256, 3), 256, 0, stream>>>(wq, wk, wv, Wh);
  k_proj<<<dim3(384), 512, 0, stream>>>(xq, xk, xv, Wh, bq, bk, bv, proj, fc2);
  k_transpose_v<<<dim3(32, 8, 8), 256, 0, stream>>>(proj, xvT);
  k_attn<<<dim3(512), 256, 0, stream>>>(proj, xvT, fc2, out);
}